// Round 7
// baseline (378.035 us; speedup 1.0000x reference)
//
#include <hip/hip_runtime.h>
#include <hip/hip_bf16.h>

// B=4, N0=2048 (N=1024 diff + 1024 cond), C=768, H=12, hd=64. All fp32 I/O.
// Split-bf16 (x = hi + lo, 3 bf16-MFMA terms) for all GEMM/attention math.
//   0. weight prep: wT[n][k] split hi/lo for all 4 weight matrices
//   1. qkv both streams  [MFMA] -> split q/k (B,H,N,64) + vt (B,H,64,N) hi/lo
//   2. osp = attn(q_d,k_d,vt_d)              [MFMA] -> SPLIT (B*N,768) hi/lo
//   3. vt2 = (osp @ w_proj_diff + b)^T split [MFMA] -> (B,H,64,N) hi/lo
//   4+5 fused: P = softmax(q_c k_c^T) once;
//        out[:, :N] = P @ vt2 (fp32), osp = P @ vt_c (split)
//   6. out[:, N:] = osp @ w_proj_cond + b    [MFMA]
//
// qkv: A staged as RAW FP32 via gl16 (no reg round-trip, no ds_write);
// hi/lo split happens at fragment-read time, overlapped with MFMA (VALU and
// matrix pipes are separate). All staging is gl16; 2-phase dbuf, 64 KB LDS.
// Swizzles: B chunks ^((row>>1)&3) (16B, 64B rows); A chunks ^(row&7)
// (16B, 128B rows). Both applied source-side + read-side (rule #21).

#define C_DIM 768
#define HEADS 12
#define HD 64
#define NSEQ 1024
#define BATCH 4
#define SZC 3145728  // BATCH*HEADS*NSEQ*HD

typedef short bf16x8 __attribute__((ext_vector_type(8)));
typedef float f32x4 __attribute__((ext_vector_type(4)));
typedef unsigned int u32x4v __attribute__((ext_vector_type(4)));

typedef __attribute__((address_space(3))) unsigned int lds_u32_t;
typedef __attribute__((address_space(1))) const unsigned int glb_u32_t;

__device__ __forceinline__ void gl16(const void* g, void* l) {
  __builtin_amdgcn_global_load_lds((glb_u32_t*)g, (lds_u32_t*)l, 16, 0, 0);
}

__device__ __forceinline__ unsigned short f2bf(float x) {
  __hip_bfloat16 h = __float2bfloat16(x);
  return *reinterpret_cast<unsigned short*>(&h);
}
__device__ __forceinline__ float bf2f(unsigned short u) {
  __hip_bfloat16 h = *reinterpret_cast<__hip_bfloat16*>(&u);
  return __bfloat162float(h);
}
__device__ __forceinline__ void split2(float x, unsigned short& hi, unsigned short& lo) {
  unsigned short h = f2bf(x);
  lo = f2bf(x - bf2f(h));
  hi = h;
}

// ---------------------------------------------------------------------------
// Weight prep: w (K x N fp32, row-major) -> wT hi/lo (N x K bf16 split).
// ---------------------------------------------------------------------------
__global__ __launch_bounds__(256) void split_wT_k(
    const float* __restrict__ w, int K, int N,
    unsigned short* __restrict__ th, unsigned short* __restrict__ tl)
{
  __shared__ float T[32][33];
  const int n0 = blockIdx.x * 32, k0 = blockIdx.y * 32;
  const int tx = threadIdx.x, ty = threadIdx.y;
#pragma unroll
  for (int i = 0; i < 4; ++i) {
    int k = ty + i * 8;
    T[k][tx] = w[(size_t)(k0 + k) * N + n0 + tx];
  }
  __syncthreads();
#pragma unroll
  for (int i = 0; i < 4; ++i) {
    int n = ty + i * 8;
    float v = T[tx][n];
    unsigned short hi, lo;
    split2(v, hi, lo);
    th[(size_t)(n0 + n) * K + k0 + tx] = hi;
    tl[(size_t)(n0 + n) * K + k0 + tx] = lo;
  }
}

// ---------------------------------------------------------------------------
// QKV GEMM, 2-phase dbuf, all-gl16 staging. A = raw fp32 [128][32]f (128B
// rows, chunk^(row&7)); split to hi/lo at frag-read. B = pre-split bf16
// [128][32]us (64B rows, chunk^((row>>1)&3)). 128x128, BK=32, 4 waves.
// Per 32KB buffer: A fp32 @0 (16KB), Bh @16384 (8KB), Bl @24576 (8KB).
// ---------------------------------------------------------------------------
__global__ __launch_bounds__(256) void qkv_gemm_k(
    const float* __restrict__ x,
    const unsigned short* __restrict__ wdh, const unsigned short* __restrict__ wdl,
    const unsigned short* __restrict__ wch, const unsigned short* __restrict__ wcl,
    unsigned short* __restrict__ ws_split)
{
  __shared__ __attribute__((aligned(16))) unsigned char lds[65536];  // 64 KB

  const int tid = threadIdx.x;
  const int lane = tid & 63;
  const int wave = tid >> 6;
  const int wr = wave >> 1, wc = wave & 1;
  const int arow = lane & 15, agrp = lane >> 4;

  // XCD-aware bijective swizzle: nwg = 1152, /8 = 144
  int flat = blockIdx.x + 18 * blockIdx.y + 576 * blockIdx.z;
  flat = (flat & 7) * 144 + (flat >> 3);
  const int bx = flat % 18;
  const int by = (flat / 18) & 31;
  const int half = flat / 576;

  const int m0 = by * 128;
  const int b = m0 >> 10, nloc = m0 & 1023;
  const int c0 = bx * 128;
  const unsigned short* __restrict__ BTh = half ? wch : wdh;
  const unsigned short* __restrict__ BTl = half ? wcl : wdl;
  const float* __restrict__ Abase = x + (size_t)(b * 2048 + half * 1024 + nloc) * 768;

  // B staging lanes: row gr (64/call), 16B chunk gc pre-swizzled
  const int gr = tid >> 2, gc = (tid & 3) ^ ((tid >> 3) & 3);
  const unsigned short* gBh = BTh + (size_t)(c0 + gr) * 768 + gc * 8;
  const unsigned short* gBl = BTl + (size_t)(c0 + gr) * 768 + gc * 8;

  // A staging lanes: row asr (32/call), 16B chunk asc pre-swizzled ^(row&7)
  const int asr = tid >> 3, asc = tid & 7;
  const float* gA = Abase + (size_t)asr * 768 + ((asc ^ (asr & 7)) * 4);

  const int wbo = wave * 1024;  // per-wave gl16 dest byte offset (all regions)

  f32x4 acc[4][4];
#pragma unroll
  for (int i = 0; i < 4; ++i)
#pragma unroll
    for (int j = 0; j < 4; ++j) acc[i][j] = f32x4{0.f, 0.f, 0.f, 0.f};

  auto stage = [&](int k0, int bo) {
    // A fp32: 4 calls x 32 rows x 128B
    gl16(gA + k0,             lds + bo + 0     + wbo);
    gl16(gA + k0 + 32 * 768,  lds + bo + 4096  + wbo);
    gl16(gA + k0 + 64 * 768,  lds + bo + 8192  + wbo);
    gl16(gA + k0 + 96 * 768,  lds + bo + 12288 + wbo);
    // B split bf16: 2 calls each x 64 rows x 64B
    gl16(gBh + k0,            lds + bo + 16384 + wbo);
    gl16(gBh + k0 + 64 * 768, lds + bo + 20480 + wbo);
    gl16(gBl + k0,            lds + bo + 24576 + wbo);
    gl16(gBl + k0 + 64 * 768, lds + bo + 28672 + wbo);
  };

  // prologue
  stage(0, 0);
  asm volatile("s_waitcnt vmcnt(0)" ::: "memory");
  __builtin_amdgcn_s_barrier();

  int cur = 0;
  for (int t = 0; t < 24; ++t) {
    const int bo = cur * 32768;
    if (t < 23) stage((t + 1) * 32, bo ^ 32768);

    // A fragments: fp32 ds_read + in-reg split (overlaps MFMA on VALU pipe)
    bf16x8 ah[4], al[4], bhf[4], blf[4];
#pragma unroll
    for (int mf = 0; mf < 4; ++mf) {
      const int row = wr * 64 + mf * 16 + arow;
      const int cbase = 2 * agrp;
      f32x4 f0 = *(const f32x4*)(lds + bo + row * 128 + ((cbase ^ (row & 7)) << 4));
      f32x4 f1 = *(const f32x4*)(lds + bo + row * 128 + (((cbase + 1) ^ (row & 7)) << 4));
      float fa[8] = {f0[0], f0[1], f0[2], f0[3], f1[0], f1[1], f1[2], f1[3]};
      unsigned short hv[8], lv[8];
#pragma unroll
      for (int j = 0; j < 8; ++j) split2(fa[j], hv[j], lv[j]);
      ah[mf] = *(bf16x8*)hv;
      al[mf] = *(bf16x8*)lv;
    }
#pragma unroll
    for (int nf = 0; nf < 4; ++nf) {
      const int row = wc * 64 + nf * 16 + arow;
      const int off = bo + 16384 + row * 64 + ((agrp ^ ((row >> 1) & 3)) << 4);
      bhf[nf] = *(const bf16x8*)(lds + off);
      blf[nf] = *(const bf16x8*)(lds + off + 8192);
    }
#pragma unroll
    for (int mf = 0; mf < 4; ++mf)
#pragma unroll
      for (int nf = 0; nf < 4; ++nf) {
        acc[mf][nf] = __builtin_amdgcn_mfma_f32_16x16x32_bf16(ah[mf], bhf[nf], acc[mf][nf], 0, 0, 0);
        acc[mf][nf] = __builtin_amdgcn_mfma_f32_16x16x32_bf16(ah[mf], blf[nf], acc[mf][nf], 0, 0, 0);
        acc[mf][nf] = __builtin_amdgcn_mfma_f32_16x16x32_bf16(al[mf], bhf[nf], acc[mf][nf], 0, 0, 0);
      }

    if (t < 23) {
      asm volatile("s_waitcnt vmcnt(0)" ::: "memory");
      __builtin_amdgcn_s_barrier();
      cur ^= 1;
    }
  }

  // epilogue: scatter split q/k (row-major) and v (transposed)
#pragma unroll
  for (int nf = 0; nf < 4; ++nf) {
    const int cg = c0 + wc * 64 + nf * 16 + arow;
    const int t = cg / 768;
    const int rem = cg - t * 768;
    const int h = rem >> 6;
    const int d = rem & 63;
    unsigned short* hi_arr = ws_split + (size_t)(half * 6 + t * 2) * SZC;
    unsigned short* lo_arr = hi_arr + SZC;
    const size_t bh_ = (size_t)(b * HEADS + h);
#pragma unroll
    for (int mf = 0; mf < 4; ++mf) {
#pragma unroll
      for (int ri = 0; ri < 4; ++ri) {
        const int n = nloc + wr * 64 + mf * 16 + agrp * 4 + ri;
        unsigned short hi, lo;
        split2(acc[mf][nf][ri], hi, lo);
        size_t idx;
        if (t < 2) idx = (bh_ * NSEQ + n) * HD + d;
        else       idx = (bh_ * HD + d) * NSEQ + n;
        hi_arr[idx] = hi;
        lo_arr[idx] = lo;
      }
    }
  }
}

// ---------------------------------------------------------------------------
// Proj GEMM, 2-phase dbuf, all-gl16 both sides (pre-swizzled sources).
// LDS 64 KB. EPI 1: fp32 d_out[:, N:] + bias. EPI 2: vt2 transposed split.
// ---------------------------------------------------------------------------
template <int EPI>
__global__ __launch_bounds__(256) void proj_gemm_k(
    const unsigned short* __restrict__ Ah, const unsigned short* __restrict__ Al,
    const unsigned short* __restrict__ Bh, const unsigned short* __restrict__ Bl,
    const float* __restrict__ bias,
    float* __restrict__ outf,
    unsigned short* __restrict__ vt_hi, unsigned short* __restrict__ vt_lo)
{
  __shared__ __attribute__((aligned(16))) unsigned short lds[32768];  // 64 KB

  const int tid = threadIdx.x;
  const int lane = tid & 63;
  const int wave = tid >> 6;
  const int wr = wave >> 1, wc = wave & 1;
  const int arow = lane & 15, agrp = lane >> 4;

  int flat = blockIdx.x + 6 * blockIdx.y;
  flat = (flat & 7) * 24 + (flat >> 3);
  const int bx = flat % 6;
  const int by = flat / 6;
  const int m0 = by * 128;
  const int c0 = bx * 128;

  const int gr = tid >> 2, gc = (tid & 3) ^ ((tid >> 3) & 3);
  const unsigned short* gAh = Ah + (size_t)(m0 + gr) * 768 + gc * 8;
  const unsigned short* gAl = Al + (size_t)(m0 + gr) * 768 + gc * 8;
  const unsigned short* gBh = Bh + (size_t)(c0 + gr) * 768 + gc * 8;
  const unsigned short* gBl = Bl + (size_t)(c0 + gr) * 768 + gc * 8;
  const int wo = wave * 512;

  f32x4 acc[4][4];
#pragma unroll
  for (int i = 0; i < 4; ++i)
#pragma unroll
    for (int j = 0; j < 4; ++j) acc[i][j] = f32x4{0.f, 0.f, 0.f, 0.f};

  auto stage8 = [&](int k0, int bo) {
    gl16(gAh + k0, lds + bo + wo);
    gl16(gAh + k0 + 64 * 768, lds + bo + wo + 2048);
    gl16(gAl + k0, lds + bo + 4096 + wo);
    gl16(gAl + k0 + 64 * 768, lds + bo + 4096 + wo + 2048);
    gl16(gBh + k0, lds + bo + 8192 + wo);
    gl16(gBh + k0 + 64 * 768, lds + bo + 8192 + wo + 2048);
    gl16(gBl + k0, lds + bo + 12288 + wo);
    gl16(gBl + k0 + 64 * 768, lds + bo + 12288 + wo + 2048);
  };

  stage8(0, 0);
  asm volatile("s_waitcnt vmcnt(0)" ::: "memory");
  __builtin_amdgcn_s_barrier();

  int cur = 0;
  for (int t = 0; t < 24; ++t) {
    const int bo = cur * 16384;
    const int nbo = bo ^ 16384;
    if (t < 23) stage8((t + 1) * 32, nbo);

    bf16x8 ah[4], al[4], bhf[4], blf[4];
#pragma unroll
    for (int mf = 0; mf < 4; ++mf) {
      const int row = wr * 64 + mf * 16 + arow;
      const int off = bo + row * 32 + ((agrp ^ ((row >> 1) & 3)) << 3);
      ah[mf] = *(const bf16x8*)(lds + off);
      al[mf] = *(const bf16x8*)(lds + 4096 + off);
    }
#pragma unroll
    for (int nf = 0; nf < 4; ++nf) {
      const int row = wc * 64 + nf * 16 + arow;
      const int off = bo + row * 32 + ((agrp ^ ((row >> 1) & 3)) << 3);
      bhf[nf] = *(const bf16x8*)(lds + 8192 + off);
      blf[nf] = *(const bf16x8*)(lds + 12288 + off);
    }
#pragma unroll
    for (int mf = 0; mf < 4; ++mf)
#pragma unroll
      for (int nf = 0; nf < 4; ++nf) {
        acc[mf][nf] = __builtin_amdgcn_mfma_f32_16x16x32_bf16(ah[mf], bhf[nf], acc[mf][nf], 0, 0, 0);
        acc[mf][nf] = __builtin_amdgcn_mfma_f32_16x16x32_bf16(ah[mf], blf[nf], acc[mf][nf], 0, 0, 0);
        acc[mf][nf] = __builtin_amdgcn_mfma_f32_16x16x32_bf16(al[mf], bhf[nf], acc[mf][nf], 0, 0, 0);
      }

    if (t < 23) {
      asm volatile("s_waitcnt vmcnt(0)" ::: "memory");
      __builtin_amdgcn_s_barrier();
      cur ^= 1;
    }
  }

  if constexpr (EPI == 1) {
#pragma unroll
    for (int nf = 0; nf < 4; ++nf) {
      const int cg = c0 + wc * 64 + nf * 16 + arow;
      const float bv = bias[cg];
#pragma unroll
      for (int mf = 0; mf < 4; ++mf) {
#pragma unroll
        for (int ri = 0; ri < 4; ++ri) {
          const int m = m0 + wr * 64 + mf * 16 + agrp * 4 + ri;
          const int bb = m >> 10, n = m & 1023;
          outf[(size_t)bb * (2048 * 768) + (size_t)(1024 + n) * 768 + cg] =
              acc[mf][nf][ri] + bv;
        }
      }
    }
  } else {  // EPI == 2: transposed split (B,H,64,N)
#pragma unroll
    for (int nf = 0; nf < 4; ++nf) {
      const int cg = c0 + wc * 64 + nf * 16 + arow;
      const int h = cg >> 6, d = cg & 63;
      const float bv = bias[cg];
#pragma unroll
      for (int mf = 0; mf < 4; ++mf) {
#pragma unroll
        for (int ri = 0; ri < 4; ++ri) {
          const int m = m0 + wr * 64 + mf * 16 + agrp * 4 + ri;
          const int bb = m >> 10, n = m & 1023;
          unsigned short hi, lo;
          split2(acc[mf][nf][ri] + bv, hi, lo);
          const size_t idx = ((size_t)(bb * HEADS + h) * HD + d) * NSEQ + n;
          vt_hi[idx] = hi;
          vt_lo[idx] = lo;
        }
      }
    }
  }
}

// ---------------------------------------------------------------------------
// Flash attention (split-bf16), unchanged (proven).
// ---------------------------------------------------------------------------
__global__ __launch_bounds__(256) void attn_single_k(
    const unsigned short* __restrict__ q_hi, const unsigned short* __restrict__ q_lo,
    const unsigned short* __restrict__ k_hi, const unsigned short* __restrict__ k_lo,
    const unsigned short* __restrict__ vt_hi, const unsigned short* __restrict__ vt_lo,
    unsigned short* __restrict__ osph, unsigned short* __restrict__ ospl)
{
  __shared__ __attribute__((aligned(16))) unsigned char lds[50176];
  unsigned char* const ldsK_hi = lds;
  unsigned char* const ldsK_lo = lds + 8192;
  unsigned char* const ldsV_hi = lds + 16384;
  unsigned char* const ldsV_lo = lds + 24576;

  const int tid  = threadIdx.x;
  const int wave = tid >> 6;
  const int lane = tid & 63;

  int flat = blockIdx.x + 16 * blockIdx.y + 192 * blockIdx.z;
  flat = (flat & 7) * 96 + (flat >> 3);
  const int bxq = flat & 15;
  const int h = (flat >> 4) % 12;
  const int b = flat / 192;
  const int bh = b * HEADS + h;
  const int q0 = bxq * 64 + wave * 16;

  unsigned int* const ldsP = (unsigned int*)(lds + 32768) + wave * (16 * 68);

  const int arow = lane & 15;
  const int agrp = lane >> 4;

  bf16x8 qh[2], ql[2];
  {
    const unsigned short* qp = q_hi + ((size_t)bh * NSEQ + q0 + arow) * HD + agrp * 8;
    qh[0] = *(const bf16x8*)qp;
    qh[1] = *(const bf16x8*)(qp + 32);
    const unsigned short* qp2 = q_lo + ((size_t)bh * NSEQ + q0 + arow) * HD + agrp * 8;
    ql[0] = *(const bf16x8*)qp2;
    ql[1] = *(const bf16x8*)(qp2 + 32);
  }

  f32x4 acc[4];
#pragma unroll
  for (int i = 0; i < 4; ++i) acc[i] = f32x4{0.f, 0.f, 0.f, 0.f};
  float m_run[4], l_run[4];
#pragma unroll
  for (int r = 0; r < 4; ++r) { m_run[r] = -3.0e38f; l_run[r] = 0.f; }

  const int sr = tid >> 3, sc = tid & 7;
  const int swzc = ((sc ^ (sr & 7)) << 3);
  const size_t kbase = (size_t)bh * NSEQ * HD;
  const size_t vbase = (size_t)bh * HD * NSEQ;
  const unsigned short* gKh = k_hi + kbase + (size_t)sr * 64 + swzc;
  const unsigned short* gKl = k_lo + kbase + (size_t)sr * 64 + swzc;
  const unsigned short* gVh = vt_hi + vbase + (size_t)sr * NSEQ + swzc;
  const unsigned short* gVl = vt_lo + vbase + (size_t)sr * NSEQ + swzc;
  const int ldsw = (wave * 8) * 128;

  for (int j0 = 0; j0 < NSEQ; j0 += 64) {
    __syncthreads();
    gl16(gKh + j0 * 64, ldsK_hi + ldsw);
    gl16(gKh + j0 * 64 + 2048, ldsK_hi + ldsw + 4096);
    gl16(gKl + j0 * 64, ldsK_lo + ldsw);
    gl16(gKl + j0 * 64 + 2048, ldsK_lo + ldsw + 4096);
    gl16(gVh + j0, ldsV_hi + ldsw);
    gl16(gVh + j0 + 32 * NSEQ, ldsV_hi + ldsw + 4096);
    gl16(gVl + j0, ldsV_lo + ldsw);
    gl16(gVl + j0 + 32 * NSEQ, ldsV_lo + ldsw + 4096);
    __syncthreads();

    f32x4 s[4];
#pragma unroll
    for (int nt = 0; nt < 4; ++nt) s[nt] = f32x4{0.f, 0.f, 0.f, 0.f};
#pragma unroll
    for (int ks = 0; ks < 2; ++ks) {
#pragma unroll
      for (int nt = 0; nt < 4; ++nt) {
        const int krow = nt * 16 + arow;
        const int chunk = ks * 4 + agrp;
        const int off = krow * 128 + (((chunk ^ (krow & 7)) << 4));
        bf16x8 bh_ = *(const bf16x8*)(ldsK_hi + off);
        bf16x8 bl_ = *(const bf16x8*)(ldsK_lo + off);
        s[nt] = __builtin_amdgcn_mfma_f32_16x16x32_bf16(qh[ks], bh_, s[nt], 0, 0, 0);
        s[nt] = __builtin_amdgcn_mfma_f32_16x16x32_bf16(qh[ks], bl_, s[nt], 0, 0, 0);
        s[nt] = __builtin_amdgcn_mfma_f32_16x16x32_bf16(ql[ks], bh_, s[nt], 0, 0, 0);
      }
    }
#pragma unroll
    for (int nt = 0; nt < 4; ++nt) s[nt] *= 0.125f;

    float corr[4], rsum[4];
#pragma unroll
    for (int r = 0; r < 4; ++r) {
      float mx = fmaxf(fmaxf(s[0][r], s[1][r]), fmaxf(s[2][r], s[3][r]));
      mx = fmaxf(mx, __shfl_xor(mx, 1, 64));
      mx = fmaxf(mx, __shfl_xor(mx, 2, 64));
      mx = fmaxf(mx, __shfl_xor(mx, 4, 64));
      mx = fmaxf(mx, __shfl_xor(mx, 8, 64));
      float mnew = fmaxf(m_run[r], mx);
      corr[r] = __expf(m_run[r] - mnew);
      m_run[r] = mnew;
      rsum[r] = 0.f;
    }
#pragma unroll
    for (int nt = 0; nt < 4; ++nt) {
#pragma unroll
      for (int r = 0; r < 4; ++r) {
        float p = __expf(s[nt][r] - m_run[r]);
        rsum[r] += p;
        unsigned short ph, pl;
        split2(p, ph, pl);
        ldsP[(agrp * 4 + r) * 68 + nt * 16 + arow] =
            (unsigned int)ph | ((unsigned int)pl << 16);
      }
    }
#pragma unroll
    for (int r = 0; r < 4; ++r) {
      float sm = rsum[r];
      sm += __shfl_xor(sm, 1, 64);
      sm += __shfl_xor(sm, 2, 64);
      sm += __shfl_xor(sm, 4, 64);
      sm += __shfl_xor(sm, 8, 64);
      l_run[r] = l_run[r] * corr[r] + sm;
#pragma unroll
      for (int nt2 = 0; nt2 < 4; ++nt2) acc[nt2][r] *= corr[r];
    }

#pragma unroll
    for (int kk = 0; kk < 2; ++kk) {
      const unsigned int* prow = ldsP + arow * 68 + kk * 32 + agrp * 8;
      u32x4v w0 = *(const u32x4v*)prow;
      u32x4v w1 = *(const u32x4v*)(prow + 4);
      bf16x8 pa_h, pa_l;
#pragma unroll
      for (int i = 0; i < 4; ++i) {
        pa_h[i]     = (short)(w0[i] & 0xffffu);
        pa_l[i]     = (short)(w0[i] >> 16);
        pa_h[4 + i] = (short)(w1[i] & 0xffffu);
        pa_l[4 + i] = (short)(w1[i] >> 16);
      }
#pragma unroll
      for (int nt2 = 0; nt2 < 4; ++nt2) {
        const int vrow = nt2 * 16 + arow;
        const int chunk = kk * 4 + agrp;
        const int off = vrow * 128 + (((chunk ^ (vrow & 7)) << 4));
        bf16x8 vh_ = *(const bf16x8*)(ldsV_hi + off);
        bf16x8 vl_ = *(const bf16x8*)(ldsV_lo + off);
        acc[nt2] = __builtin_amdgcn_mfma_f32_16x16x32_bf16(pa_h, vh_, acc[nt2], 0, 0, 0);
        acc[nt2] = __builtin_amdgcn_mfma_f32_16x16x32_bf16(pa_h, vl_, acc[nt2], 0, 0, 0);
        acc[nt2] = __builtin_amdgcn_mfma_f32_16x16x32_bf16(pa_l, vh_, acc[nt2], 0, 0, 0);
      }
    }
  }

#pragma unroll
  for (int r = 0; r < 4; ++r) {
    const float inv = 1.f / l_run[r];
    const int n = q0 + agrp * 4 + r;
    const size_t obase = ((size_t)(b * NSEQ + n)) * C_DIM + h * HD + arow;
#pragma unroll
    for (int nt2 = 0; nt2 < 4; ++nt2) {
      unsigned short hi, lo;
      split2(acc[nt2][r] * inv, hi, lo);
      osph[obase + nt2 * 16] = hi;
      ospl[obase + nt2 * 16] = lo;
    }
  }
}

// ---------------------------------------------------------------------------
// Fused attention (steps 4+5), unchanged (proven).
// ---------------------------------------------------------------------------
__global__ __launch_bounds__(256) void attn_fused_k(
    const unsigned short* __restrict__ q_hi, const unsigned short* __restrict__ q_lo,
    const unsigned short* __restrict__ k_hi, const unsigned short* __restrict__ k_lo,
    const unsigned short* __restrict__ vAh_, const unsigned short* __restrict__ vAl_,
    const unsigned short* __restrict__ vBh_, const unsigned short* __restrict__ vBl_,
    float* __restrict__ out1,
    unsigned short* __restrict__ osph, unsigned short* __restrict__ ospl)
{
  __shared__ __attribute__((aligned(16))) unsigned char lds[66560];
  unsigned char* const ldsK_hi = lds;
  unsigned char* const ldsK_lo = lds + 8192;
  unsigned char* const ldsA_hi = lds + 16384;
  unsigned char* const ldsA_lo = lds + 24576;
  unsigned char* const ldsB_hi = lds + 32768;
  unsigned char* const ldsB_lo = lds + 40960;

  const int tid  = threadIdx.x;
  const int wave = tid >> 6;
  const int lane = tid & 63;

  int flat = blockIdx.x + 16 * blockIdx.y + 192 * blockIdx.z;
  flat = (flat & 7) * 96 + (flat >> 3);
  const int bxq = flat & 15;
  const int h = (flat >> 4) % 12;
  const int b = flat / 192;
  const int bh = b * HEADS + h;
  const int q0 = bxq * 64 + wave * 16;

  unsigned int* const ldsP = (unsigned int*)(lds + 49152) + wave * (16 * 68);

  const int arow = lane & 15;
  const int agrp = lane >> 4;

  bf16x8 qh[2], ql[2];
  {
    const unsigned short* qp = q_hi + ((size_t)bh * NSEQ + q0 + arow) * HD + agrp * 8;
    qh[0] = *(const bf16x8*)qp;
    qh[1] = *(const bf16x8*)(qp + 32);
    const unsigned short* qp2 = q_lo + ((size_t)bh * NSEQ + q0 + arow) * HD + agrp * 8;
    ql[0] = *(const bf16x8*)qp2;
    ql[1] = *(const bf16x8*)(qp2 + 32);
  }

  f32x4 acc1[4], acc2[4];
#pragma unroll
  for (int i = 0; i < 4; ++i) {
    acc1[i] = f32x4{0.f, 0.f, 0.f, 0.f};
    acc2[i] = f32x4{0.f, 0.f, 0.f, 0.f};
  }
  float m_run[4], l_run[4];
#pragma unroll
  for (int r = 0; r < 4; ++r) { m_run[r] = -3.0e38f; l_run[r] = 0.f; }

  const int sr = tid >> 3, sc = tid & 7;
  const int swzc = ((sc ^ (sr & 7)) << 3);
  const size_t kbase = (size_t)bh * NSEQ * HD;
  const size_t vbase = (size_t)bh * HD * NSEQ;
  const unsigned short* gKh = k_hi + kbase + (size_t)sr * 64 + swzc;
  const unsigned short* gKl = k_lo + kbase + (size_t)sr * 64 + swzc;
  const unsigned short* gAh = vAh_ + vbase + (size_t)sr * NSEQ + swzc;
  const unsigned short* gAl = vAl_ + vbase + (size_t)sr * NSEQ + swzc;
  const unsigned short* gBh = vBh_ + vbase + (size_t)sr * NSEQ + swzc;
  const unsigned short* gBl = vBl_ + vbase + (size_t)sr * NSEQ + swzc;
  const int ldsw = (wave * 8) * 128;

  for (int j0 = 0; j0 < NSEQ; j0 += 64) {
    __syncthreads();
    gl16(gKh + j0 * 64, ldsK_hi + ldsw);
    gl16(gKh + j0 * 64 + 2048, ldsK_hi + ldsw + 4096);
    gl16(gKl + j0 * 64, ldsK_lo + ldsw);
    gl16(gKl + j0 * 64 + 2048, ldsK_lo + ldsw + 4096);
    gl16(gAh + j0, ldsA_hi + ldsw);
    gl16(gAh + j0 + 32 * NSEQ, ldsA_hi + ldsw + 4096);
    gl16(gAl + j0, ldsA_lo + ldsw);
    gl16(gAl + j0 + 32 * NSEQ, ldsA_lo + ldsw + 4096);
    gl16(gBh + j0, ldsB_hi + ldsw);
    gl16(gBh + j0 + 32 * NSEQ, ldsB_hi + ldsw + 4096);
    gl16(gBl + j0, ldsB_lo + ldsw);
    gl16(gBl + j0 + 32 * NSEQ, ldsB_lo + ldsw + 4096);
    __syncthreads();

    f32x4 s[4];
#pragma unroll
    for (int nt = 0; nt < 4; ++nt) s[nt] = f32x4{0.f, 0.f, 0.f, 0.f};
#pragma unroll
    for (int ks = 0; ks < 2; ++ks) {
#pragma unroll
      for (int nt = 0; nt < 4; ++nt) {
        const int krow = nt * 16 + arow;
        const int chunk = ks * 4 + agrp;
        const int off = krow * 128 + (((chunk ^ (krow & 7)) << 4));
        bf16x8 bh_ = *(const bf16x8*)(ldsK_hi + off);
        bf16x8 bl_ = *(const bf16x8*)(ldsK_lo + off);
        s[nt] = __builtin_amdgcn_mfma_f32_16x16x32_bf16(qh[ks], bh_, s[nt], 0, 0, 0);
        s[nt] = __builtin_amdgcn_mfma_f32_16x16x32_bf16(qh[ks], bl_, s[nt], 0, 0, 0);
        s[nt] = __builtin_amdgcn_mfma_f32_16x16x32_bf16(ql[ks], bh_, s[nt], 0, 0, 0);
      }
    }
#pragma unroll
    for (int nt = 0; nt < 4; ++nt) s[nt] *= 0.125f;

    float corr[4], rsum[4];
#pragma unroll
    for (int r = 0; r < 4; ++r) {
      float mx = fmaxf(fmaxf(s[0][r], s[1][r]), fmaxf(s[2][r], s[3][r]));
      mx = fmaxf(mx, __shfl_xor(mx, 1, 64));
      mx = fmaxf(mx, __shfl_xor(mx, 2, 64));
      mx = fmaxf(mx, __shfl_xor(mx, 4, 64));
      mx = fmaxf(mx, __shfl_xor(mx, 8, 64));
      float mnew = fmaxf(m_run[r], mx);
      corr[r] = __expf(m_run[r] - mnew);
      m_run[r] = mnew;
      rsum[r] = 0.f;
    }
#pragma unroll
    for (int nt = 0; nt < 4; ++nt) {
#pragma unroll
      for (int r = 0; r < 4; ++r) {
        float p = __expf(s[nt][r] - m_run[r]);
        rsum[r] += p;
        unsigned short ph, pl;
        split2(p, ph, pl);
        ldsP[(agrp * 4 + r) * 68 + nt * 16 + arow] =
            (unsigned int)ph | ((unsigned int)pl << 16);
      }
    }
#pragma unroll
    for (int r = 0; r < 4; ++r) {
      float sm = rsum[r];
      sm += __shfl_xor(sm, 1, 64);
      sm += __shfl_xor(sm, 2, 64);
      sm += __shfl_xor(sm, 4, 64);
      sm += __shfl_xor(sm, 8, 64);
      l_run[r] = l_run[r] * corr[r] + sm;
#pragma unroll
      for (int nt2 = 0; nt2 < 4; ++nt2) {
        acc1[nt2][r] *= corr[r];
        acc2[nt2][r] *= corr[r];
      }
    }

#pragma unroll
    for (int kk = 0; kk < 2; ++kk) {
      const unsigned int* prow = ldsP + arow * 68 + kk * 32 + agrp * 8;
      u32x4v w0 = *(const u32x4v*)prow;
      u32x4v w1 = *(const u32x4v*)(prow + 4);
      bf16x8 pa_h, pa_l;
#pragma unroll
      for (int i = 0; i < 4; ++i) {
        pa_h[i]     = (short)(w0[i] & 0xffffu);
        pa_l[i]     = (short)(w0[i] >> 16);
        pa_h[4 + i] = (short)(w1[i] & 0xffffu);
        pa_l[4 + i] = (short)(w1[i] >> 16);
      }
#pragma unroll
      for (int nt2 = 0; nt2 < 4; ++nt2) {
        const int vrow = nt2 * 16 + arow;
        const int chunk = kk * 4 + agrp;
        const int off = vrow * 128 + (((chunk ^ (vrow & 7)) << 4));
        bf16x8 vh_ = *(const bf16x8*)(ldsA_hi + off);
        bf16x8 vl_ = *(const bf16x8*)(ldsA_lo + off);
        acc1[nt2] = __builtin_amdgcn_mfma_f32_16x16x32_bf16(pa_h, vh_, acc1[nt2], 0, 0, 0);
        acc1[nt2] = __builtin_amdgcn_mfma_f32_16x16x32_bf16(pa_h, vl_, acc1[nt2], 0, 0, 0);
        acc1[nt2] = __builtin_amdgcn_mfma_f32_16x16x32_bf16(pa_l, vh_, acc1[nt2], 0, 0, 0);
        bf16x8 uh_ = *(const bf16x8*)(ldsB_hi + off);
        bf16x8 ul_ = *(const bf16x8*)(ldsB_lo + off);
        acc2[nt2] = __builtin_amdgcn_mfma_f32_16x16x32_bf16(pa_h, uh_, acc2[nt2], 0, 0, 0);
        acc2[nt2] = __builtin_amdgcn_mfma_f32_16x16x32_bf16(pa_h, ul_, acc2[nt2], 0, 0, 0);
        acc2[nt2] = __builtin_amdgcn_mfma_f32_16x16x32_bf16(pa_l, uh_, acc2[nt2], 0, 0, 0);
      }
    }
  }

#pragma unroll
  for (int r = 0; r < 4; ++r) {
    const float inv = 1.f / l_run[r];
    const int n = q0 + agrp * 4 + r;
    float* rowp = out1 + (size_t)b * (2048 * C_DIM) + (size_t)n * C_DIM + h * HD + arow;
    const size_t obase = ((size_t)(b * NSEQ + n)) * C_DIM + h * HD + arow;
#pragma unroll
    for (int nt2 = 0; nt2 < 4; ++nt2) {
      rowp[nt2 * 16] = acc1[nt2][r] * inv;
      unsigned short hi, lo;
      split2(acc2[nt2][r] * inv, hi, lo);
      osph[obase + nt2 * 16] = hi;
      ospl[obase + nt2 * 16] = lo;
    }
  }
}

// ---------------------------------------------------------------------------
extern "C" void kernel_launch(void* const* d_in, const int* in_sizes, int n_in,
                              void* d_out, int out_size, void* d_ws, size_t ws_size,
                              hipStream_t stream)
{
  const float* x           = (const float*)d_in[0];
  const float* w_qkv_diff  = (const float*)d_in[1];
  const float* w_qkv_cond  = (const float*)d_in[2];
  const float* w_proj_diff = (const float*)d_in[3];
  const float* b_proj_diff = (const float*)d_in[4];
  const float* w_proj_cond = (const float*)d_in[5];
  const float* b_proj_cond = (const float*)d_in[6];
  float* out = (float*)d_out;

  const size_t SZ = SZC;
  const size_t WQ = 2304 * 768;
  const size_t WP = 768 * 768;
  unsigned short* sw = (unsigned short*)d_ws;
  unsigned short* qd_hi  = sw + 0 * SZ;
  unsigned short* qd_lo  = sw + 1 * SZ;
  unsigned short* kd_hi  = sw + 2 * SZ;
  unsigned short* kd_lo  = sw + 3 * SZ;
  unsigned short* vtd_hi = sw + 4 * SZ;
  unsigned short* vtd_lo = sw + 5 * SZ;
  unsigned short* qc_hi  = sw + 6 * SZ;
  unsigned short* qc_lo  = sw + 7 * SZ;
  unsigned short* kc_hi  = sw + 8 * SZ;
  unsigned short* kc_lo  = sw + 9 * SZ;
  unsigned short* vtc_hi = sw + 10 * SZ;
  unsigned short* vtc_lo = sw + 11 * SZ;
  unsigned short* wqdT_h = sw + 12 * SZ;
  unsigned short* wqdT_l = wqdT_h + WQ;
  unsigned short* wqcT_h = wqdT_l + WQ;
  unsigned short* wqcT_l = wqcT_h + WQ;
  unsigned short* wpdT_h = wqcT_l + WQ;
  unsigned short* wpdT_l = wpdT_h + WP;
  unsigned short* wpcT_h = wpdT_l + WP;
  unsigned short* wpcT_l = wpcT_h + WP;
  unsigned short* osph = wqdT_h;          // aliases wq*T (dead after qkv)
  unsigned short* ospl = wqdT_h + SZ;
  unsigned short* vt2_hi = qd_hi;         // aliases q_d (dead after step 2)
  unsigned short* vt2_lo = qd_lo;

  // 0. weight prep
  split_wT_k<<<dim3(72, 24), dim3(32, 8), 0, stream>>>(w_qkv_diff, 768, 2304, wqdT_h, wqdT_l);
  split_wT_k<<<dim3(72, 24), dim3(32, 8), 0, stream>>>(w_qkv_cond, 768, 2304, wqcT_h, wqcT_l);
  split_wT_k<<<dim3(24, 24), dim3(32, 8), 0, stream>>>(w_proj_diff, 768, 768, wpdT_h, wpdT_l);
  split_wT_k<<<dim3(24, 24), dim3(32, 8), 0, stream>>>(w_proj_cond, 768, 768, wpcT_h, wpcT_l);

  // 1. qkv both streams
  qkv_gemm_k<<<dim3(18, 32, 2), 256, 0, stream>>>(
      x, wqdT_h, wqdT_l, wqcT_h, wqcT_l, sw);

  // 2. attn_diff -> osp split
  attn_single_k<<<dim3(16, 12, 4), 256, 0, stream>>>(
      qd_hi, qd_lo, kd_hi, kd_lo, vtd_hi, vtd_lo, osph, ospl);

  // 3. (osp @ w_proj_diff + b)^T split -> vt2
  proj_gemm_k<2><<<dim3(6, 32), 256, 0, stream>>>(
      osph, ospl, wpdT_h, wpdT_l, b_proj_diff, nullptr, vt2_hi, vt2_lo);

  // 4+5. fused attn_cond: P @ vt2 -> out[:, :N] fp32 ; P @ vt_c -> osp split
  attn_fused_k<<<dim3(16, 12, 4), 256, 0, stream>>>(
      qc_hi, qc_lo, kc_hi, kc_lo, vt2_hi, vt2_lo, vtc_hi, vtc_lo, out, osph, ospl);

  // 6. out[:, N:] = osp @ w_proj_cond + b
  proj_gemm_k<1><<<dim3(6, 32), 256, 0, stream>>>(
      osph, ospl, wpcT_h, wpcT_l, b_proj_cond, out, nullptr, nullptr);
}

// Round 8
// 356.351 us; speedup vs baseline: 1.0608x; 1.0608x over previous
//
#include <hip/hip_runtime.h>
#include <hip/hip_bf16.h>

// B=4, N0=2048 (N=1024 diff + 1024 cond), C=768, H=12, hd=64. All fp32 I/O.
// Split-bf16 (x = hi + lo, 3 bf16-MFMA terms) for all GEMM/attention math.
//   0. weight prep: wT split hi/lo (x4); x split hi/lo -> d_out scratch
//   1. qkv both streams  [MFMA] -> split q/k (B,H,N,64) + vt (B,H,64,N) hi/lo
//   2. osp = attn(q_d,k_d,vt_d)              [MFMA] -> SPLIT (B*N,768) hi/lo
//   3. vt2 = (osp @ w_proj_diff + b)^T split [MFMA] -> (B,H,64,N) hi/lo
//   4+5 fused: P = softmax(q_c k_c^T) once;
//        out[:, :N] = P @ vt2 (fp32), osp = P @ vt_c (split)
//   6. out[:, N:] = osp @ w_proj_cond + b    [MFMA]
//
// All GEMMs share one 2-phase dbuf loop (gemm2_k<EPI>): all-gl16 staging of
// pre-split bf16 both sides, chunk^((row>>1)&3) involution (0 conflicts,
// verified R5), one vmcnt(0)+s_barrier per K-step. qkv uses an L2-chunked
// block mapping (3bx x 8by per XCD => ~4.3MB working set). x is pre-split
// into d_out (dead until step 4; fully overwritten by steps 4+6).

#define C_DIM 768
#define HEADS 12
#define HD 64
#define NSEQ 1024
#define BATCH 4
#define SZC 3145728  // BATCH*HEADS*NSEQ*HD

typedef short bf16x8 __attribute__((ext_vector_type(8)));
typedef float f32x4 __attribute__((ext_vector_type(4)));
typedef unsigned int u32x4v __attribute__((ext_vector_type(4)));

typedef __attribute__((address_space(3))) unsigned int lds_u32_t;
typedef __attribute__((address_space(1))) const unsigned int glb_u32_t;

__device__ __forceinline__ void gl16(const void* g, void* l) {
  __builtin_amdgcn_global_load_lds((glb_u32_t*)g, (lds_u32_t*)l, 16, 0, 0);
}

__device__ __forceinline__ unsigned short f2bf(float x) {
  __hip_bfloat16 h = __float2bfloat16(x);
  return *reinterpret_cast<unsigned short*>(&h);
}
__device__ __forceinline__ float bf2f(unsigned short u) {
  __hip_bfloat16 h = *reinterpret_cast<__hip_bfloat16*>(&u);
  return __bfloat162float(h);
}
__device__ __forceinline__ void split2(float x, unsigned short& hi, unsigned short& lo) {
  unsigned short h = f2bf(x);
  lo = f2bf(x - bf2f(h));
  hi = h;
}

// ---------------------------------------------------------------------------
// Weight prep: w (K x N fp32, row-major) -> wT hi/lo (N x K bf16 split).
// ---------------------------------------------------------------------------
__global__ __launch_bounds__(256) void split_wT_k(
    const float* __restrict__ w, int K, int N,
    unsigned short* __restrict__ th, unsigned short* __restrict__ tl)
{
  __shared__ float T[32][33];
  const int n0 = blockIdx.x * 32, k0 = blockIdx.y * 32;
  const int tx = threadIdx.x, ty = threadIdx.y;
#pragma unroll
  for (int i = 0; i < 4; ++i) {
    int k = ty + i * 8;
    T[k][tx] = w[(size_t)(k0 + k) * N + n0 + tx];
  }
  __syncthreads();
#pragma unroll
  for (int i = 0; i < 4; ++i) {
    int n = ty + i * 8;
    float v = T[tx][n];
    unsigned short hi, lo;
    split2(v, hi, lo);
    th[(size_t)(n0 + n) * K + k0 + tx] = hi;
    tl[(size_t)(n0 + n) * K + k0 + tx] = lo;
  }
}

// ---------------------------------------------------------------------------
// x prep: elementwise split of x (6.29M fp32) -> xh, xl. grid 3072 x 256.
// ---------------------------------------------------------------------------
__global__ __launch_bounds__(256) void split_x_k(
    const float* __restrict__ x,
    unsigned short* __restrict__ xh, unsigned short* __restrict__ xl)
{
  const size_t i = ((size_t)blockIdx.x * 256 + threadIdx.x) * 8;
  float4 f0 = *(const float4*)(x + i);
  float4 f1 = *(const float4*)(x + i + 4);
  float fa[8] = {f0.x, f0.y, f0.z, f0.w, f1.x, f1.y, f1.z, f1.w};
  unsigned short hv[8], lv[8];
#pragma unroll
  for (int j = 0; j < 8; ++j) split2(fa[j], hv[j], lv[j]);
  *(bf16x8*)(xh + i) = *(bf16x8*)hv;
  *(bf16x8*)(xl + i) = *(bf16x8*)lv;
}

// ---------------------------------------------------------------------------
// Unified split-bf16 GEMM, 2-phase dbuf, all-gl16 both sides (pre-swizzled
// sources, chunk^((row>>1)&3)). 128x128 tile, BK=32, 4 waves, LDS 64 KB.
// EPI 0: qkv (A = pre-split x, B selected by half; L2-chunked mapping;
//        epilogue scatters split q/k row-major + vt transposed)
// EPI 1: proj -> fp32 d_out[:, N:] + bias
// EPI 2: proj -> vt2 transposed split + bias
// ---------------------------------------------------------------------------
template <int EPI>
__global__ __launch_bounds__(256) void gemm2_k(
    const unsigned short* __restrict__ Ah, const unsigned short* __restrict__ Al,
    const unsigned short* __restrict__ Bh0, const unsigned short* __restrict__ Bl0,
    const unsigned short* __restrict__ Bh1, const unsigned short* __restrict__ Bl1,
    const float* __restrict__ bias,
    unsigned short* __restrict__ ws_split,
    float* __restrict__ outf,
    unsigned short* __restrict__ vt_hi, unsigned short* __restrict__ vt_lo)
{
  __shared__ __attribute__((aligned(16))) unsigned short lds[32768];  // 64 KB

  const int tid = threadIdx.x;
  const int lane = tid & 63;
  const int wave = tid >> 6;
  const int wr = wave >> 1, wc = wave & 1;
  const int arow = lane & 15, agrp = lane >> 4;

  int bx, by, half;
  if constexpr (EPI == 0) {
    // L2-chunked bijective mapping: per XCD, 6 chunks of (3 bx x 8 by).
    int orig = blockIdx.x + 18 * blockIdx.y + 576 * blockIdx.z;  // [0,1152)
    int xcd = orig & 7, l = orig >> 3;       // l in [0,144)
    int g = xcd * 6 + (l / 24);              // chunk id [0,48)
    int r = l % 24;
    int rest = g / 6;                        // [0,8)
    bx = (g % 6) * 3 + (r % 3);              // [0,18)
    by = (rest & 3) * 8 + (r / 3);           // [0,32)
    half = rest >> 2;                        // {0,1}
  } else {
    int flat = blockIdx.x + 6 * blockIdx.y;  // nwg = 192
    flat = (flat & 7) * 24 + (flat >> 3);
    bx = flat % 6;
    by = flat / 6;
    half = 0;
  }

  const int m0 = by * 128;
  const int b = m0 >> 10, nloc = m0 & 1023;
  const int c0 = bx * 128;
  const unsigned short* __restrict__ Bh = (EPI == 0 && half) ? Bh1 : Bh0;
  const unsigned short* __restrict__ Bl = (EPI == 0 && half) ? Bl1 : Bl0;
  const size_t Arow = (EPI == 0) ? (size_t)(b * 2048 + half * 1024 + nloc)
                                 : (size_t)m0;

  const int gr = tid >> 2, gc = (tid & 3) ^ ((tid >> 3) & 3);
  const unsigned short* gAh = Ah + (Arow + gr) * 768 + gc * 8;
  const unsigned short* gAl = Al + (Arow + gr) * 768 + gc * 8;
  const unsigned short* gBh = Bh + (size_t)(c0 + gr) * 768 + gc * 8;
  const unsigned short* gBl = Bl + (size_t)(c0 + gr) * 768 + gc * 8;
  const int wo = wave * 512;

  f32x4 acc[4][4];
#pragma unroll
  for (int i = 0; i < 4; ++i)
#pragma unroll
    for (int j = 0; j < 4; ++j) acc[i][j] = f32x4{0.f, 0.f, 0.f, 0.f};

  auto stage8 = [&](int k0, int bo) {
    gl16(gAh + k0, lds + bo + wo);
    gl16(gAh + k0 + 64 * 768, lds + bo + wo + 2048);
    gl16(gAl + k0, lds + bo + 4096 + wo);
    gl16(gAl + k0 + 64 * 768, lds + bo + 4096 + wo + 2048);
    gl16(gBh + k0, lds + bo + 8192 + wo);
    gl16(gBh + k0 + 64 * 768, lds + bo + 8192 + wo + 2048);
    gl16(gBl + k0, lds + bo + 12288 + wo);
    gl16(gBl + k0 + 64 * 768, lds + bo + 12288 + wo + 2048);
  };

  stage8(0, 0);
  asm volatile("s_waitcnt vmcnt(0)" ::: "memory");
  __builtin_amdgcn_s_barrier();

  int cur = 0;
  for (int t = 0; t < 24; ++t) {
    const int bo = cur * 16384;
    if (t < 23) stage8((t + 1) * 32, bo ^ 16384);

    bf16x8 ah[4], al[4], bhf[4], blf[4];
#pragma unroll
    for (int mf = 0; mf < 4; ++mf) {
      const int row = wr * 64 + mf * 16 + arow;
      const int off = bo + row * 32 + ((agrp ^ ((row >> 1) & 3)) << 3);
      ah[mf] = *(const bf16x8*)(lds + off);
      al[mf] = *(const bf16x8*)(lds + 4096 + off);
    }
#pragma unroll
    for (int nf = 0; nf < 4; ++nf) {
      const int row = wc * 64 + nf * 16 + arow;
      const int off = bo + row * 32 + ((agrp ^ ((row >> 1) & 3)) << 3);
      bhf[nf] = *(const bf16x8*)(lds + 8192 + off);
      blf[nf] = *(const bf16x8*)(lds + 12288 + off);
    }
#pragma unroll
    for (int mf = 0; mf < 4; ++mf)
#pragma unroll
      for (int nf = 0; nf < 4; ++nf) {
        acc[mf][nf] = __builtin_amdgcn_mfma_f32_16x16x32_bf16(ah[mf], bhf[nf], acc[mf][nf], 0, 0, 0);
        acc[mf][nf] = __builtin_amdgcn_mfma_f32_16x16x32_bf16(ah[mf], blf[nf], acc[mf][nf], 0, 0, 0);
        acc[mf][nf] = __builtin_amdgcn_mfma_f32_16x16x32_bf16(al[mf], bhf[nf], acc[mf][nf], 0, 0, 0);
      }

    if (t < 23) {
      asm volatile("s_waitcnt vmcnt(0)" ::: "memory");
      __builtin_amdgcn_s_barrier();
      cur ^= 1;
    }
  }

  if constexpr (EPI == 0) {
    // col tile never straddles q/k/v boundary (768 % 128 == 0)
    const int t_ = c0 / 768;
    const int rem0 = c0 - t_ * 768;
    unsigned short* hi_arr = ws_split + (size_t)(half * 6 + t_ * 2) * SZC;
    unsigned short* lo_arr = hi_arr + SZC;
#pragma unroll
    for (int nf = 0; nf < 4; ++nf) {
      const int rc = rem0 + wc * 64 + nf * 16 + arow;
      const int h = rc >> 6;
      const int d = rc & 63;
      const size_t bh_ = (size_t)(b * HEADS + h);
      if (t_ < 2) {
        // q/k row-major (B,H,N,64): scalar stores, stride HD over ri
#pragma unroll
        for (int mf = 0; mf < 4; ++mf) {
#pragma unroll
          for (int ri = 0; ri < 4; ++ri) {
            const int n = nloc + wr * 64 + mf * 16 + agrp * 4 + ri;
            unsigned short hi, lo;
            split2(acc[mf][nf][ri], hi, lo);
            const size_t idx = (bh_ * NSEQ + n) * HD + d;
            hi_arr[idx] = hi;
            lo_arr[idx] = lo;
          }
        }
      } else {
        // vt transposed (B,H,64,N): ri is n-contiguous -> ushort4 stores
#pragma unroll
        for (int mf = 0; mf < 4; ++mf) {
          const int n = nloc + wr * 64 + mf * 16 + agrp * 4;
          unsigned short hv[4], lv[4];
#pragma unroll
          for (int ri = 0; ri < 4; ++ri) split2(acc[mf][nf][ri], hv[ri], lv[ri]);
          const size_t idx = (bh_ * HD + d) * NSEQ + n;
          *(ushort4*)(hi_arr + idx) = *(ushort4*)hv;
          *(ushort4*)(lo_arr + idx) = *(ushort4*)lv;
        }
      }
    }
  } else if constexpr (EPI == 1) {
#pragma unroll
    for (int nf = 0; nf < 4; ++nf) {
      const int cg = c0 + wc * 64 + nf * 16 + arow;
      const float bv = bias[cg];
#pragma unroll
      for (int mf = 0; mf < 4; ++mf) {
#pragma unroll
        for (int ri = 0; ri < 4; ++ri) {
          const int m = m0 + wr * 64 + mf * 16 + agrp * 4 + ri;
          const int bb = m >> 10, n = m & 1023;
          outf[(size_t)bb * (2048 * 768) + (size_t)(1024 + n) * 768 + cg] =
              acc[mf][nf][ri] + bv;
        }
      }
    }
  } else {  // EPI == 2: transposed split (B,H,64,N), n-contiguous over ri
#pragma unroll
    for (int nf = 0; nf < 4; ++nf) {
      const int cg = c0 + wc * 64 + nf * 16 + arow;
      const int h = cg >> 6, d = cg & 63;
      const float bv = bias[cg];
#pragma unroll
      for (int mf = 0; mf < 4; ++mf) {
        const int m = m0 + wr * 64 + mf * 16 + agrp * 4;
        const int bb = m >> 10, n = m & 1023;
        unsigned short hv[4], lv[4];
#pragma unroll
        for (int ri = 0; ri < 4; ++ri) split2(acc[mf][nf][ri] + bv, hv[ri], lv[ri]);
        const size_t idx = ((size_t)(bb * HEADS + h) * HD + d) * NSEQ + n;
        *(ushort4*)(vt_hi + idx) = *(ushort4*)hv;
        *(ushort4*)(vt_lo + idx) = *(ushort4*)lv;
      }
    }
  }
}

// ---------------------------------------------------------------------------
// Flash attention (split-bf16), unchanged (proven).
// ---------------------------------------------------------------------------
__global__ __launch_bounds__(256) void attn_single_k(
    const unsigned short* __restrict__ q_hi, const unsigned short* __restrict__ q_lo,
    const unsigned short* __restrict__ k_hi, const unsigned short* __restrict__ k_lo,
    const unsigned short* __restrict__ vt_hi, const unsigned short* __restrict__ vt_lo,
    unsigned short* __restrict__ osph, unsigned short* __restrict__ ospl)
{
  __shared__ __attribute__((aligned(16))) unsigned char lds[50176];
  unsigned char* const ldsK_hi = lds;
  unsigned char* const ldsK_lo = lds + 8192;
  unsigned char* const ldsV_hi = lds + 16384;
  unsigned char* const ldsV_lo = lds + 24576;

  const int tid  = threadIdx.x;
  const int wave = tid >> 6;
  const int lane = tid & 63;

  int flat = blockIdx.x + 16 * blockIdx.y + 192 * blockIdx.z;
  flat = (flat & 7) * 96 + (flat >> 3);
  const int bxq = flat & 15;
  const int h = (flat >> 4) % 12;
  const int b = flat / 192;
  const int bh = b * HEADS + h;
  const int q0 = bxq * 64 + wave * 16;

  unsigned int* const ldsP = (unsigned int*)(lds + 32768) + wave * (16 * 68);

  const int arow = lane & 15;
  const int agrp = lane >> 4;

  bf16x8 qh[2], ql[2];
  {
    const unsigned short* qp = q_hi + ((size_t)bh * NSEQ + q0 + arow) * HD + agrp * 8;
    qh[0] = *(const bf16x8*)qp;
    qh[1] = *(const bf16x8*)(qp + 32);
    const unsigned short* qp2 = q_lo + ((size_t)bh * NSEQ + q0 + arow) * HD + agrp * 8;
    ql[0] = *(const bf16x8*)qp2;
    ql[1] = *(const bf16x8*)(qp2 + 32);
  }

  f32x4 acc[4];
#pragma unroll
  for (int i = 0; i < 4; ++i) acc[i] = f32x4{0.f, 0.f, 0.f, 0.f};
  float m_run[4], l_run[4];
#pragma unroll
  for (int r = 0; r < 4; ++r) { m_run[r] = -3.0e38f; l_run[r] = 0.f; }

  const int sr = tid >> 3, sc = tid & 7;
  const int swzc = ((sc ^ (sr & 7)) << 3);
  const size_t kbase = (size_t)bh * NSEQ * HD;
  const size_t vbase = (size_t)bh * HD * NSEQ;
  const unsigned short* gKh = k_hi + kbase + (size_t)sr * 64 + swzc;
  const unsigned short* gKl = k_lo + kbase + (size_t)sr * 64 + swzc;
  const unsigned short* gVh = vt_hi + vbase + (size_t)sr * NSEQ + swzc;
  const unsigned short* gVl = vt_lo + vbase + (size_t)sr * NSEQ + swzc;
  const int ldsw = (wave * 8) * 128;

  for (int j0 = 0; j0 < NSEQ; j0 += 64) {
    __syncthreads();
    gl16(gKh + j0 * 64, ldsK_hi + ldsw);
    gl16(gKh + j0 * 64 + 2048, ldsK_hi + ldsw + 4096);
    gl16(gKl + j0 * 64, ldsK_lo + ldsw);
    gl16(gKl + j0 * 64 + 2048, ldsK_lo + ldsw + 4096);
    gl16(gVh + j0, ldsV_hi + ldsw);
    gl16(gVh + j0 + 32 * NSEQ, ldsV_hi + ldsw + 4096);
    gl16(gVl + j0, ldsV_lo + ldsw);
    gl16(gVl + j0 + 32 * NSEQ, ldsV_lo + ldsw + 4096);
    __syncthreads();

    f32x4 s[4];
#pragma unroll
    for (int nt = 0; nt < 4; ++nt) s[nt] = f32x4{0.f, 0.f, 0.f, 0.f};
#pragma unroll
    for (int ks = 0; ks < 2; ++ks) {
#pragma unroll
      for (int nt = 0; nt < 4; ++nt) {
        const int krow = nt * 16 + arow;
        const int chunk = ks * 4 + agrp;
        const int off = krow * 128 + (((chunk ^ (krow & 7)) << 4));
        bf16x8 bh_ = *(const bf16x8*)(ldsK_hi + off);
        bf16x8 bl_ = *(const bf16x8*)(ldsK_lo + off);
        s[nt] = __builtin_amdgcn_mfma_f32_16x16x32_bf16(qh[ks], bh_, s[nt], 0, 0, 0);
        s[nt] = __builtin_amdgcn_mfma_f32_16x16x32_bf16(qh[ks], bl_, s[nt], 0, 0, 0);
        s[nt] = __builtin_amdgcn_mfma_f32_16x16x32_bf16(ql[ks], bh_, s[nt], 0, 0, 0);
      }
    }
#pragma unroll
    for (int nt = 0; nt < 4; ++nt) s[nt] *= 0.125f;

    float corr[4], rsum[4];
#pragma unroll
    for (int r = 0; r < 4; ++r) {
      float mx = fmaxf(fmaxf(s[0][r], s[1][r]), fmaxf(s[2][r], s[3][r]));
      mx = fmaxf(mx, __shfl_xor(mx, 1, 64));
      mx = fmaxf(mx, __shfl_xor(mx, 2, 64));
      mx = fmaxf(mx, __shfl_xor(mx, 4, 64));
      mx = fmaxf(mx, __shfl_xor(mx, 8, 64));
      float mnew = fmaxf(m_run[r], mx);
      corr[r] = __expf(m_run[r] - mnew);
      m_run[r] = mnew;
      rsum[r] = 0.f;
    }
#pragma unroll
    for (int nt = 0; nt < 4; ++nt) {
#pragma unroll
      for (int r = 0; r < 4; ++r) {
        float p = __expf(s[nt][r] - m_run[r]);
        rsum[r] += p;
        unsigned short ph, pl;
        split2(p, ph, pl);
        ldsP[(agrp * 4 + r) * 68 + nt * 16 + arow] =
            (unsigned int)ph | ((unsigned int)pl << 16);
      }
    }
#pragma unroll
    for (int r = 0; r < 4; ++r) {
      float sm = rsum[r];
      sm += __shfl_xor(sm, 1, 64);
      sm += __shfl_xor(sm, 2, 64);
      sm += __shfl_xor(sm, 4, 64);
      sm += __shfl_xor(sm, 8, 64);
      l_run[r] = l_run[r] * corr[r] + sm;
#pragma unroll
      for (int nt2 = 0; nt2 < 4; ++nt2) acc[nt2][r] *= corr[r];
    }

#pragma unroll
    for (int kk = 0; kk < 2; ++kk) {
      const unsigned int* prow = ldsP + arow * 68 + kk * 32 + agrp * 8;
      u32x4v w0 = *(const u32x4v*)prow;
      u32x4v w1 = *(const u32x4v*)(prow + 4);
      bf16x8 pa_h, pa_l;
#pragma unroll
      for (int i = 0; i < 4; ++i) {
        pa_h[i]     = (short)(w0[i] & 0xffffu);
        pa_l[i]     = (short)(w0[i] >> 16);
        pa_h[4 + i] = (short)(w1[i] & 0xffffu);
        pa_l[4 + i] = (short)(w1[i] >> 16);
      }
#pragma unroll
      for (int nt2 = 0; nt2 < 4; ++nt2) {
        const int vrow = nt2 * 16 + arow;
        const int chunk = kk * 4 + agrp;
        const int off = vrow * 128 + (((chunk ^ (vrow & 7)) << 4));
        bf16x8 vh_ = *(const bf16x8*)(ldsV_hi + off);
        bf16x8 vl_ = *(const bf16x8*)(ldsV_lo + off);
        acc[nt2] = __builtin_amdgcn_mfma_f32_16x16x32_bf16(pa_h, vh_, acc[nt2], 0, 0, 0);
        acc[nt2] = __builtin_amdgcn_mfma_f32_16x16x32_bf16(pa_h, vl_, acc[nt2], 0, 0, 0);
        acc[nt2] = __builtin_amdgcn_mfma_f32_16x16x32_bf16(pa_l, vh_, acc[nt2], 0, 0, 0);
      }
    }
  }

#pragma unroll
  for (int r = 0; r < 4; ++r) {
    const float inv = 1.f / l_run[r];
    const int n = q0 + agrp * 4 + r;
    const size_t obase = ((size_t)(b * NSEQ + n)) * C_DIM + h * HD + arow;
#pragma unroll
    for (int nt2 = 0; nt2 < 4; ++nt2) {
      unsigned short hi, lo;
      split2(acc[nt2][r] * inv, hi, lo);
      osph[obase + nt2 * 16] = hi;
      ospl[obase + nt2 * 16] = lo;
    }
  }
}

// ---------------------------------------------------------------------------
// Fused attention (steps 4+5), unchanged (proven).
// ---------------------------------------------------------------------------
__global__ __launch_bounds__(256) void attn_fused_k(
    const unsigned short* __restrict__ q_hi, const unsigned short* __restrict__ q_lo,
    const unsigned short* __restrict__ k_hi, const unsigned short* __restrict__ k_lo,
    const unsigned short* __restrict__ vAh_, const unsigned short* __restrict__ vAl_,
    const unsigned short* __restrict__ vBh_, const unsigned short* __restrict__ vBl_,
    float* __restrict__ out1,
    unsigned short* __restrict__ osph, unsigned short* __restrict__ ospl)
{
  __shared__ __attribute__((aligned(16))) unsigned char lds[66560];
  unsigned char* const ldsK_hi = lds;
  unsigned char* const ldsK_lo = lds + 8192;
  unsigned char* const ldsA_hi = lds + 16384;
  unsigned char* const ldsA_lo = lds + 24576;
  unsigned char* const ldsB_hi = lds + 32768;
  unsigned char* const ldsB_lo = lds + 40960;

  const int tid  = threadIdx.x;
  const int wave = tid >> 6;
  const int lane = tid & 63;

  int flat = blockIdx.x + 16 * blockIdx.y + 192 * blockIdx.z;
  flat = (flat & 7) * 96 + (flat >> 3);
  const int bxq = flat & 15;
  const int h = (flat >> 4) % 12;
  const int b = flat / 192;
  const int bh = b * HEADS + h;
  const int q0 = bxq * 64 + wave * 16;

  unsigned int* const ldsP = (unsigned int*)(lds + 49152) + wave * (16 * 68);

  const int arow = lane & 15;
  const int agrp = lane >> 4;

  bf16x8 qh[2], ql[2];
  {
    const unsigned short* qp = q_hi + ((size_t)bh * NSEQ + q0 + arow) * HD + agrp * 8;
    qh[0] = *(const bf16x8*)qp;
    qh[1] = *(const bf16x8*)(qp + 32);
    const unsigned short* qp2 = q_lo + ((size_t)bh * NSEQ + q0 + arow) * HD + agrp * 8;
    ql[0] = *(const bf16x8*)qp2;
    ql[1] = *(const bf16x8*)(qp2 + 32);
  }

  f32x4 acc1[4], acc2[4];
#pragma unroll
  for (int i = 0; i < 4; ++i) {
    acc1[i] = f32x4{0.f, 0.f, 0.f, 0.f};
    acc2[i] = f32x4{0.f, 0.f, 0.f, 0.f};
  }
  float m_run[4], l_run[4];
#pragma unroll
  for (int r = 0; r < 4; ++r) { m_run[r] = -3.0e38f; l_run[r] = 0.f; }

  const int sr = tid >> 3, sc = tid & 7;
  const int swzc = ((sc ^ (sr & 7)) << 3);
  const size_t kbase = (size_t)bh * NSEQ * HD;
  const size_t vbase = (size_t)bh * HD * NSEQ;
  const unsigned short* gKh = k_hi + kbase + (size_t)sr * 64 + swzc;
  const unsigned short* gKl = k_lo + kbase + (size_t)sr * 64 + swzc;
  const unsigned short* gAh = vAh_ + vbase + (size_t)sr * NSEQ + swzc;
  const unsigned short* gAl = vAl_ + vbase + (size_t)sr * NSEQ + swzc;
  const unsigned short* gBh = vBh_ + vbase + (size_t)sr * NSEQ + swzc;
  const unsigned short* gBl = vBl_ + vbase + (size_t)sr * NSEQ + swzc;
  const int ldsw = (wave * 8) * 128;

  for (int j0 = 0; j0 < NSEQ; j0 += 64) {
    __syncthreads();
    gl16(gKh + j0 * 64, ldsK_hi + ldsw);
    gl16(gKh + j0 * 64 + 2048, ldsK_hi + ldsw + 4096);
    gl16(gKl + j0 * 64, ldsK_lo + ldsw);
    gl16(gKl + j0 * 64 + 2048, ldsK_lo + ldsw + 4096);
    gl16(gAh + j0, ldsA_hi + ldsw);
    gl16(gAh + j0 + 32 * NSEQ, ldsA_hi + ldsw + 4096);
    gl16(gAl + j0, ldsA_lo + ldsw);
    gl16(gAl + j0 + 32 * NSEQ, ldsA_lo + ldsw + 4096);
    gl16(gBh + j0, ldsB_hi + ldsw);
    gl16(gBh + j0 + 32 * NSEQ, ldsB_hi + ldsw + 4096);
    gl16(gBl + j0, ldsB_lo + ldsw);
    gl16(gBl + j0 + 32 * NSEQ, ldsB_lo + ldsw + 4096);
    __syncthreads();

    f32x4 s[4];
#pragma unroll
    for (int nt = 0; nt < 4; ++nt) s[nt] = f32x4{0.f, 0.f, 0.f, 0.f};
#pragma unroll
    for (int ks = 0; ks < 2; ++ks) {
#pragma unroll
      for (int nt = 0; nt < 4; ++nt) {
        const int krow = nt * 16 + arow;
        const int chunk = ks * 4 + agrp;
        const int off = krow * 128 + (((chunk ^ (krow & 7)) << 4));
        bf16x8 bh_ = *(const bf16x8*)(ldsK_hi + off);
        bf16x8 bl_ = *(const bf16x8*)(ldsK_lo + off);
        s[nt] = __builtin_amdgcn_mfma_f32_16x16x32_bf16(qh[ks], bh_, s[nt], 0, 0, 0);
        s[nt] = __builtin_amdgcn_mfma_f32_16x16x32_bf16(qh[ks], bl_, s[nt], 0, 0, 0);
        s[nt] = __builtin_amdgcn_mfma_f32_16x16x32_bf16(ql[ks], bh_, s[nt], 0, 0, 0);
      }
    }
#pragma unroll
    for (int nt = 0; nt < 4; ++nt) s[nt] *= 0.125f;

    float corr[4], rsum[4];
#pragma unroll
    for (int r = 0; r < 4; ++r) {
      float mx = fmaxf(fmaxf(s[0][r], s[1][r]), fmaxf(s[2][r], s[3][r]));
      mx = fmaxf(mx, __shfl_xor(mx, 1, 64));
      mx = fmaxf(mx, __shfl_xor(mx, 2, 64));
      mx = fmaxf(mx, __shfl_xor(mx, 4, 64));
      mx = fmaxf(mx, __shfl_xor(mx, 8, 64));
      float mnew = fmaxf(m_run[r], mx);
      corr[r] = __expf(m_run[r] - mnew);
      m_run[r] = mnew;
      rsum[r] = 0.f;
    }
#pragma unroll
    for (int nt = 0; nt < 4; ++nt) {
#pragma unroll
      for (int r = 0; r < 4; ++r) {
        float p = __expf(s[nt][r] - m_run[r]);
        rsum[r] += p;
        unsigned short ph, pl;
        split2(p, ph, pl);
        ldsP[(agrp * 4 + r) * 68 + nt * 16 + arow] =
            (unsigned int)ph | ((unsigned int)pl << 16);
      }
    }
#pragma unroll
    for (int r = 0; r < 4; ++r) {
      float sm = rsum[r];
      sm += __shfl_xor(sm, 1, 64);
      sm += __shfl_xor(sm, 2, 64);
      sm += __shfl_xor(sm, 4, 64);
      sm += __shfl_xor(sm, 8, 64);
      l_run[r] = l_run[r] * corr[r] + sm;
#pragma unroll
      for (int nt2 = 0; nt2 < 4; ++nt2) {
        acc1[nt2][r] *= corr[r];
        acc2[nt2][r] *= corr[r];
      }
    }

#pragma unroll
    for (int kk = 0; kk < 2; ++kk) {
      const unsigned int* prow = ldsP + arow * 68 + kk * 32 + agrp * 8;
      u32x4v w0 = *(const u32x4v*)prow;
      u32x4v w1 = *(const u32x4v*)(prow + 4);
      bf16x8 pa_h, pa_l;
#pragma unroll
      for (int i = 0; i < 4; ++i) {
        pa_h[i]     = (short)(w0[i] & 0xffffu);
        pa_l[i]     = (short)(w0[i] >> 16);
        pa_h[4 + i] = (short)(w1[i] & 0xffffu);
        pa_l[4 + i] = (short)(w1[i] >> 16);
      }
#pragma unroll
      for (int nt2 = 0; nt2 < 4; ++nt2) {
        const int vrow = nt2 * 16 + arow;
        const int chunk = kk * 4 + agrp;
        const int off = vrow * 128 + (((chunk ^ (vrow & 7)) << 4));
        bf16x8 vh_ = *(const bf16x8*)(ldsA_hi + off);
        bf16x8 vl_ = *(const bf16x8*)(ldsA_lo + off);
        acc1[nt2] = __builtin_amdgcn_mfma_f32_16x16x32_bf16(pa_h, vh_, acc1[nt2], 0, 0, 0);
        acc1[nt2] = __builtin_amdgcn_mfma_f32_16x16x32_bf16(pa_h, vl_, acc1[nt2], 0, 0, 0);
        acc1[nt2] = __builtin_amdgcn_mfma_f32_16x16x32_bf16(pa_l, vh_, acc1[nt2], 0, 0, 0);
        bf16x8 uh_ = *(const bf16x8*)(ldsB_hi + off);
        bf16x8 ul_ = *(const bf16x8*)(ldsB_lo + off);
        acc2[nt2] = __builtin_amdgcn_mfma_f32_16x16x32_bf16(pa_h, uh_, acc2[nt2], 0, 0, 0);
        acc2[nt2] = __builtin_amdgcn_mfma_f32_16x16x32_bf16(pa_h, ul_, acc2[nt2], 0, 0, 0);
        acc2[nt2] = __builtin_amdgcn_mfma_f32_16x16x32_bf16(pa_l, uh_, acc2[nt2], 0, 0, 0);
      }
    }
  }

#pragma unroll
  for (int r = 0; r < 4; ++r) {
    const float inv = 1.f / l_run[r];
    const int n = q0 + agrp * 4 + r;
    float* rowp = out1 + (size_t)b * (2048 * C_DIM) + (size_t)n * C_DIM + h * HD + arow;
    const size_t obase = ((size_t)(b * NSEQ + n)) * C_DIM + h * HD + arow;
#pragma unroll
    for (int nt2 = 0; nt2 < 4; ++nt2) {
      rowp[nt2 * 16] = acc1[nt2][r] * inv;
      unsigned short hi, lo;
      split2(acc2[nt2][r] * inv, hi, lo);
      osph[obase + nt2 * 16] = hi;
      ospl[obase + nt2 * 16] = lo;
    }
  }
}

// ---------------------------------------------------------------------------
extern "C" void kernel_launch(void* const* d_in, const int* in_sizes, int n_in,
                              void* d_out, int out_size, void* d_ws, size_t ws_size,
                              hipStream_t stream)
{
  const float* x           = (const float*)d_in[0];
  const float* w_qkv_diff  = (const float*)d_in[1];
  const float* w_qkv_cond  = (const float*)d_in[2];
  const float* w_proj_diff = (const float*)d_in[3];
  const float* b_proj_diff = (const float*)d_in[4];
  const float* w_proj_cond = (const float*)d_in[5];
  const float* b_proj_cond = (const float*)d_in[6];
  float* out = (float*)d_out;

  const size_t SZ = SZC;
  const size_t WQ = 2304 * 768;
  const size_t WP = 768 * 768;
  unsigned short* sw = (unsigned short*)d_ws;
  unsigned short* qd_hi  = sw + 0 * SZ;
  unsigned short* qd_lo  = sw + 1 * SZ;
  unsigned short* kd_hi  = sw + 2 * SZ;
  unsigned short* kd_lo  = sw + 3 * SZ;
  unsigned short* vtd_hi = sw + 4 * SZ;
  unsigned short* vtd_lo = sw + 5 * SZ;
  unsigned short* qc_hi  = sw + 6 * SZ;
  unsigned short* qc_lo  = sw + 7 * SZ;
  unsigned short* kc_hi  = sw + 8 * SZ;
  unsigned short* kc_lo  = sw + 9 * SZ;
  unsigned short* vtc_hi = sw + 10 * SZ;
  unsigned short* vtc_lo = sw + 11 * SZ;
  unsigned short* wqdT_h = sw + 12 * SZ;
  unsigned short* wqdT_l = wqdT_h + WQ;
  unsigned short* wqcT_h = wqdT_l + WQ;
  unsigned short* wqcT_l = wqcT_h + WQ;
  unsigned short* wpdT_h = wqcT_l + WQ;
  unsigned short* wpdT_l = wpdT_h + WP;
  unsigned short* wpcT_h = wpdT_l + WP;
  unsigned short* wpcT_l = wpcT_h + WP;
  unsigned short* osph = wqdT_h;          // aliases wq*T (dead after qkv)
  unsigned short* ospl = wqdT_h + SZ;
  unsigned short* vt2_hi = qd_hi;         // aliases q_d (dead after step 2)
  unsigned short* vt2_lo = qd_lo;
  // x split scratch: d_out (25.2 MB, dead until step 4; fully overwritten
  // by steps 4 and 6 afterwards). xh = 2SZ us, xl = 2SZ us.
  unsigned short* xh = (unsigned short*)d_out;
  unsigned short* xl = xh + 2 * SZ;

  // 0. weight + x prep
  split_wT_k<<<dim3(72, 24), dim3(32, 8), 0, stream>>>(w_qkv_diff, 768, 2304, wqdT_h, wqdT_l);
  split_wT_k<<<dim3(72, 24), dim3(32, 8), 0, stream>>>(w_qkv_cond, 768, 2304, wqcT_h, wqcT_l);
  split_wT_k<<<dim3(24, 24), dim3(32, 8), 0, stream>>>(w_proj_diff, 768, 768, wpdT_h, wpdT_l);
  split_wT_k<<<dim3(24, 24), dim3(32, 8), 0, stream>>>(w_proj_cond, 768, 768, wpcT_h, wpcT_l);
  split_x_k<<<dim3(3072), 256, 0, stream>>>(x, xh, xl);

  // 1. qkv both streams
  gemm2_k<0><<<dim3(18, 32, 2), 256, 0, stream>>>(
      xh, xl, wqdT_h, wqdT_l, wqcT_h, wqcT_l, nullptr, sw, nullptr, nullptr, nullptr);

  // 2. attn_diff -> osp split
  attn_single_k<<<dim3(16, 12, 4), 256, 0, stream>>>(
      qd_hi, qd_lo, kd_hi, kd_lo, vtd_hi, vtd_lo, osph, ospl);

  // 3. (osp @ w_proj_diff + b)^T split -> vt2
  gemm2_k<2><<<dim3(6, 32), 256, 0, stream>>>(
      osph, ospl, wpdT_h, wpdT_l, nullptr, nullptr, b_proj_diff, nullptr, nullptr, vt2_hi, vt2_lo);

  // 4+5. fused attn_cond: P @ vt2 -> out[:, :N] fp32 ; P @ vt_c -> osp split
  attn_fused_k<<<dim3(16, 12, 4), 256, 0, stream>>>(
      qc_hi, qc_lo, kc_hi, kc_lo, vt2_hi, vt2_lo, vtc_hi, vtc_lo, out, osph, ospl);

  // 6. out[:, N:] = osp @ w_proj_cond + b
  gemm2_k<1><<<dim3(6, 32), 256, 0, stream>>>(
      osph, ospl, wpcT_h, wpcT_l, nullptr, nullptr, b_proj_cond, nullptr, out, nullptr, nullptr);
}